// Round 1
// baseline (1119.306 us; speedup 1.0000x reference)
//
#include <hip/hip_runtime.h>
#include <stdint.h>

typedef unsigned short u16;
typedef __attribute__((ext_vector_type(8))) short short8;
typedef __attribute__((ext_vector_type(4))) float floatx4;

// ---------- helpers ----------
__device__ __forceinline__ u16 f2bf(float f) {
    union { float f; uint32_t u; } v; v.f = f;
    uint32_t u = v.u;
    uint32_t r = (u + 0x7fffu + ((u >> 16) & 1u)) >> 16;
    return (u16)r;
}

// ---------- elementwise convert f32 -> bf16 ----------
__global__ void cvt_f32_bf16(const float* __restrict__ in, u16* __restrict__ out, int n) {
    int idx = blockIdx.x * 256 + threadIdx.x;
    if (idx < n) out[idx] = f2bf(in[idx]);
}

// ---------- transpose + convert: in[R,C] f32 -> out[Cp,R] bf16 (pad rows >= C with 0) ----------
__global__ void transpose_cvt(const float* __restrict__ in, u16* __restrict__ out,
                              int R, int C, int Cp) {
    __shared__ float tile[32][33];
    int c0 = blockIdx.x * 32, r0 = blockIdx.y * 32;
    int tx = threadIdx.x, ty = threadIdx.y;   // 32 x 8
    #pragma unroll
    for (int i = 0; i < 32; i += 8) {
        int r = r0 + ty + i, c = c0 + tx;
        float v = (c < C && r < R) ? in[(size_t)r * C + c] : 0.f;
        tile[ty + i][tx] = v;
    }
    __syncthreads();
    #pragma unroll
    for (int i = 0; i < 32; i += 8) {
        int c = c0 + ty + i, r = r0 + tx;
        if (c < Cp && r < R) out[(size_t)c * R + r] = f2bf(tile[tx][ty + i]);
    }
}

// ---------- bf16 MFMA GEMM: C[M,N] = A[M,K] * Bt[N,K]^T, fp32 out ----------
// EPI 0: plain store. EPI 1: softplus(acc + bias[col]).
template<int EPI>
__global__ __launch_bounds__(256, 2) void gemm_bf16(
    const u16* __restrict__ A, const u16* __restrict__ Bt,
    float* __restrict__ C, int M, int N, int K, const float* __restrict__ bias)
{
    __shared__ __align__(16) short lds_a[128 * 32];
    __shared__ __align__(16) short lds_b[128 * 32];
    const int tid = threadIdx.x;
    const int m0 = blockIdx.y * 128;
    const int n0 = blockIdx.x * 128;
    const int wave = tid >> 6, lane = tid & 63;
    const int wm = (wave & 1) * 64, wn = (wave >> 1) * 64;
    const int q = lane >> 4, r16 = lane & 15;
    const int srow = tid >> 2;   // 0..63
    const int skq  = tid & 3;    // k-offset group: skq*8 bf16

    floatx4 acc[4][4];
    #pragma unroll
    for (int i = 0; i < 4; ++i)
        #pragma unroll
        for (int j = 0; j < 4; ++j)
            acc[i][j] = (floatx4){0.f, 0.f, 0.f, 0.f};

    for (int k0 = 0; k0 < K; k0 += 32) {
        uint4 va0 = *(const uint4*)(A + (size_t)(m0 + srow)      * K + k0 + skq * 8);
        uint4 va1 = *(const uint4*)(A + (size_t)(m0 + srow + 64) * K + k0 + skq * 8);
        uint4 vb0 = *(const uint4*)(Bt + (size_t)(n0 + srow)      * K + k0 + skq * 8);
        uint4 vb1 = *(const uint4*)(Bt + (size_t)(n0 + srow + 64) * K + k0 + skq * 8);
        __syncthreads();
        *(uint4*)(lds_a + srow * 32 + skq * 8)        = va0;
        *(uint4*)(lds_a + (srow + 64) * 32 + skq * 8) = va1;
        *(uint4*)(lds_b + srow * 32 + skq * 8)        = vb0;
        *(uint4*)(lds_b + (srow + 64) * 32 + skq * 8) = vb1;
        __syncthreads();

        short8 af[4], bf[4];
        #pragma unroll
        for (int mt = 0; mt < 4; ++mt)
            af[mt] = *(const short8*)(lds_a + (wm + mt * 16 + r16) * 32 + q * 8);
        #pragma unroll
        for (int nt = 0; nt < 4; ++nt)
            bf[nt] = *(const short8*)(lds_b + (wn + nt * 16 + r16) * 32 + q * 8);
        #pragma unroll
        for (int mt = 0; mt < 4; ++mt)
            #pragma unroll
            for (int nt = 0; nt < 4; ++nt)
                acc[mt][nt] = __builtin_amdgcn_mfma_f32_16x16x32_bf16(
                    af[mt], bf[nt], acc[mt][nt], 0, 0, 0);
    }

    #pragma unroll
    for (int mt = 0; mt < 4; ++mt)
        #pragma unroll
        for (int nt = 0; nt < 4; ++nt) {
            int gcol = n0 + wn + nt * 16 + r16;
            #pragma unroll
            for (int r = 0; r < 4; ++r) {
                int grow = m0 + wm + mt * 16 + q * 4 + r;
                float v = acc[mt][nt][r];
                if (EPI == 1) {
                    v += bias[gcol];
                    v = (v > 20.f) ? v : log1pf(__expf(v));
                }
                C[(size_t)grow * N + gcol] = v;
            }
        }
}

// ---------- causal depthwise conv (K=4) + silu; writes f32 and bf16 ----------
__global__ void conv_silu_kernel(const float* __restrict__ xz, const float* __restrict__ cw,
                                 const float* __restrict__ cb, float* __restrict__ xf,
                                 u16* __restrict__ xbf) {
    int idx = blockIdx.x * 256 + threadIdx.x;   // < 4096*2048
    int d = idx & 2047;
    int row = idx >> 11;          // b*L + l
    int l = row & 2047;
    float s = cb[d];
    #pragma unroll
    for (int k = 0; k < 4; ++k) {
        int ll = l + k - 3;
        if (ll >= 0) s += xz[(size_t)(row + k - 3) * 4096 + d] * cw[d * 4 + k];
    }
    float v = s / (1.f + __expf(-s));
    xf[idx] = v;
    xbf[idx] = f2bf(v);
}

// ---------- extract dt_r (cols 0..63 of x_dbl) as bf16 ----------
__global__ void cvt_dtr_kernel(const float* __restrict__ xdbl, u16* __restrict__ dtr) {
    int idx = blockIdx.x * 256 + threadIdx.x;  // < 4096*64
    int row = idx >> 6, c = idx & 63;
    dtr[idx] = f2bf(xdbl[(size_t)row * 256 + c]);
}

// ---------- selective scan ----------
// rows = (b,d) pairs: 4096 total. 16 lanes/row, 4 states/lane, 8 rows/block(128 thr).
__global__ __launch_bounds__(128) void scan_kernel(
    const float* __restrict__ dt, const float* __restrict__ xdbl,
    const float* __restrict__ xssm, const float* __restrict__ A_log,
    const float* __restrict__ Dp, float* __restrict__ y1)
{
    const int tid = threadIdx.x;
    const int lane = tid & 63, wave = tid >> 6;
    const int g = lane & 15, rw = lane >> 4;
    const int row = blockIdx.x * 8 + wave * 4 + rw;   // 0..4095
    const int b = row >> 11, d = row & 2047;
    const float LOG2E = 1.44269504088896340736f;

    float a2[4];
    #pragma unroll
    for (int k = 0; k < 4; ++k)
        a2[k] = -__expf(A_log[d * 64 + 4 * g + k]) * LOG2E;   // A * log2(e)

    const size_t rbase = ((size_t)b * 2048) * 2048 + d;
    const float* dt_p = dt + rbase;
    const float* x_p  = xssm + rbase;
    float*       y_p  = y1 + rbase;
    const size_t xb = ((size_t)b * 2048) * 256 + 64 + 4 * g;
    const float* B_p = xdbl + xb;
    const float* C_p = xdbl + xb + 64;
    const float Dd = Dp[d];

    float h0 = 0.f, h1 = 0.f, h2 = 0.f, h3 = 0.f;
    float dt_v = dt_p[0], x_v = x_p[0];
    float4 Bv = *(const float4*)B_p;
    float4 Cv = *(const float4*)C_p;

    for (int t = 0; t < 2048; ++t) {
        int t2 = (t < 2047) ? t + 1 : 2047;
        float dt_n = dt_p[(size_t)t2 * 2048];
        float x_n  = x_p[(size_t)t2 * 2048];
        float4 B_n = *(const float4*)(B_p + (size_t)t2 * 256);
        float4 C_n = *(const float4*)(C_p + (size_t)t2 * 256);

        float dtx = dt_v * x_v;
        float dA0 = exp2f(a2[0] * dt_v);
        float dA1 = exp2f(a2[1] * dt_v);
        float dA2 = exp2f(a2[2] * dt_v);
        float dA3 = exp2f(a2[3] * dt_v);
        h0 = fmaf(dA0, h0, dtx * Bv.x);
        h1 = fmaf(dA1, h1, dtx * Bv.y);
        h2 = fmaf(dA2, h2, dtx * Bv.z);
        h3 = fmaf(dA3, h3, dtx * Bv.w);
        float p = fmaf(h0, Cv.x, fmaf(h1, Cv.y, fmaf(h2, Cv.z, h3 * Cv.w)));
        p += __shfl_xor(p, 1, 64);
        p += __shfl_xor(p, 2, 64);
        p += __shfl_xor(p, 4, 64);
        p += __shfl_xor(p, 8, 64);
        if (g == 0) y_p[(size_t)t * 2048] = fmaf(x_v, Dd, p);

        dt_v = dt_n; x_v = x_n; Bv = B_n; Cv = C_n;
    }
}

// ---------- yf = bf16( y1 * silu(z) ) ----------
__global__ void fuse_kernel(const float* __restrict__ y1, const float* __restrict__ xz,
                            u16* __restrict__ yf) {
    int idx = blockIdx.x * 256 + threadIdx.x;  // < 4096*2048
    int d = idx & 2047;
    int row = idx >> 11;
    float z = xz[(size_t)row * 4096 + 2048 + d];
    float y = y1[idx] * (z / (1.f + __expf(-z)));
    yf[idx] = f2bf(y);
}

// ---------- host launch ----------
extern "C" void kernel_launch(void* const* d_in, const int* in_sizes, int n_in,
                              void* d_out, int out_size, void* d_ws, size_t ws_size,
                              hipStream_t stream) {
    const float* u     = (const float*)d_in[0];
    const float* W_in  = (const float*)d_in[1];
    const float* convw = (const float*)d_in[2];
    const float* convb = (const float*)d_in[3];
    const float* W_x   = (const float*)d_in[4];
    const float* W_dt  = (const float*)d_in[5];
    const float* b_dt  = (const float*)d_in[6];
    const float* A_log = (const float*)d_in[7];
    const float* Dvec  = (const float*)d_in[8];
    const float* W_out = (const float*)d_in[9];
    float* out = (float*)d_out;

    char* w = (char*)d_ws;
    size_t off = 0;
    auto alloc = [&](size_t bytes) -> void* {
        void* p = w + off;
        off = (off + bytes + 255) & ~(size_t)255;
        return p;
    };
    u16*   u_bf   = (u16*)  alloc((size_t)4096 * 1024 * 2);
    u16*   WinT   = (u16*)  alloc((size_t)4096 * 1024 * 2);
    u16*   WxT    = (u16*)  alloc((size_t)256 * 2048 * 2);
    u16*   WdtT   = (u16*)  alloc((size_t)2048 * 64 * 2);
    u16*   WoutT  = (u16*)  alloc((size_t)1024 * 2048 * 2);
    float* xz     = (float*)alloc((size_t)4096 * 4096 * 4);
    float* xssm_f = (float*)alloc((size_t)4096 * 2048 * 4);
    u16*   xssm_b = (u16*)  alloc((size_t)4096 * 2048 * 2);
    float* xdbl   = (float*)alloc((size_t)4096 * 256 * 4);
    u16*   dtr_bf = (u16*)  alloc((size_t)4096 * 64 * 2);
    float* dt_f   = (float*)alloc((size_t)4096 * 2048 * 4);
    float* y1     = (float*)alloc((size_t)4096 * 2048 * 4);
    u16*   yf     = (u16*)  alloc((size_t)4096 * 2048 * 2);

    // pre-passes: convert / transpose weights to bf16
    cvt_f32_bf16<<<16384, 256, 0, stream>>>(u, u_bf, 4096 * 1024);
    transpose_cvt<<<dim3(128, 32), dim3(32, 8), 0, stream>>>(W_in, WinT, 1024, 4096, 4096);
    transpose_cvt<<<dim3(8, 64),  dim3(32, 8), 0, stream>>>(W_x,   WxT,  2048, 192, 256);
    transpose_cvt<<<dim3(64, 2),  dim3(32, 8), 0, stream>>>(W_dt,  WdtT, 64, 2048, 2048);
    transpose_cvt<<<dim3(32, 64), dim3(32, 8), 0, stream>>>(W_out, WoutT, 2048, 1024, 1024);

    // GEMM1: xz = u @ W_in   [4096,1024]x[1024,4096]
    gemm_bf16<0><<<dim3(32, 32), 256, 0, stream>>>(u_bf, WinT, xz, 4096, 4096, 1024, nullptr);

    // conv + silu
    conv_silu_kernel<<<32768, 256, 0, stream>>>(xz, convw, convb, xssm_f, xssm_b);

    // GEMM2: x_dbl = x_ssm @ W_x (N padded 192->256)
    gemm_bf16<0><<<dim3(2, 32), 256, 0, stream>>>(xssm_b, WxT, xdbl, 4096, 256, 2048, nullptr);

    // dt_r -> bf16
    cvt_dtr_kernel<<<1024, 256, 0, stream>>>(xdbl, dtr_bf);

    // GEMM3: dt = softplus(dt_r @ W_dt + b_dt)
    gemm_bf16<1><<<dim3(16, 32), 256, 0, stream>>>(dtr_bf, WdtT, dt_f, 4096, 2048, 64, b_dt);

    // selective scan -> y1 = y_ssm + x_ssm * D
    scan_kernel<<<512, 128, 0, stream>>>(dt_f, xdbl, xssm_f, A_log, Dvec, y1);

    // yf = bf16(y1 * silu(z))
    fuse_kernel<<<32768, 256, 0, stream>>>(y1, xz, yf);

    // GEMM4: out = yf @ W_out
    gemm_bf16<0><<<dim3(8, 32), 256, 0, stream>>>(yf, WoutT, out, 4096, 1024, 2048, nullptr);
}

// Round 2
// 708.889 us; speedup vs baseline: 1.5790x; 1.5790x over previous
//
#include <hip/hip_runtime.h>
#include <stdint.h>

typedef unsigned short u16;
typedef __attribute__((ext_vector_type(8))) short short8;
typedef __attribute__((ext_vector_type(4))) float floatx4;

#define LOG2E 1.44269504088896340736f

// ---------- helpers ----------
__device__ __forceinline__ u16 f2bf(float f) {
    union { float f; uint32_t u; } v; v.f = f;
    uint32_t u = v.u;
    uint32_t r = (u + 0x7fffu + ((u >> 16) & 1u)) >> 16;
    return (u16)r;
}
__device__ __forceinline__ float silu(float x) { return x / (1.f + __expf(-x)); }

// ---------- elementwise convert f32 -> bf16 ----------
__global__ void cvt_f32_bf16(const float* __restrict__ in, u16* __restrict__ out, int n) {
    int idx = blockIdx.x * 256 + threadIdx.x;
    if (idx < n) out[idx] = f2bf(in[idx]);
}

// ---------- transpose + convert: in[R,C] f32 -> out[Cp,R] bf16 (pad rows >= C with 0) ----------
__global__ void transpose_cvt(const float* __restrict__ in, u16* __restrict__ out,
                              int R, int C, int Cp) {
    __shared__ float tile[32][33];
    int c0 = blockIdx.x * 32, r0 = blockIdx.y * 32;
    int tx = threadIdx.x, ty = threadIdx.y;   // 32 x 8
    #pragma unroll
    for (int i = 0; i < 32; i += 8) {
        int r = r0 + ty + i, c = c0 + tx;
        float v = (c < C && r < R) ? in[(size_t)r * C + c] : 0.f;
        tile[ty + i][tx] = v;
    }
    __syncthreads();
    #pragma unroll
    for (int i = 0; i < 32; i += 8) {
        int c = c0 + ty + i, r = r0 + tx;
        if (c < Cp && r < R) out[(size_t)c * R + r] = f2bf(tile[tx][ty + i]);
    }
}

// ---------- bf16 MFMA GEMM: C[M,N] = A[M,K] * Bt[N,K]^T, fp32 out ----------
// EPI 0: plain store. EPI 1: softplus(acc + bias[col]). EPI 2: softplus(acc + bias[row]).
template<int EPI>
__global__ __launch_bounds__(256, 2) void gemm_bf16(
    const u16* __restrict__ A, const u16* __restrict__ Bt,
    float* __restrict__ C, int M, int N, int K, const float* __restrict__ bias)
{
    __shared__ __align__(16) short lds_a[128 * 32];
    __shared__ __align__(16) short lds_b[128 * 32];
    const int tid = threadIdx.x;
    const int m0 = blockIdx.y * 128;
    const int n0 = blockIdx.x * 128;
    const int wave = tid >> 6, lane = tid & 63;
    const int wm = (wave & 1) * 64, wn = (wave >> 1) * 64;
    const int q = lane >> 4, r16 = lane & 15;
    const int srow = tid >> 2;   // 0..63
    const int skq  = tid & 3;    // k-offset group: skq*8 bf16

    floatx4 acc[4][4];
    #pragma unroll
    for (int i = 0; i < 4; ++i)
        #pragma unroll
        for (int j = 0; j < 4; ++j)
            acc[i][j] = (floatx4){0.f, 0.f, 0.f, 0.f};

    for (int k0 = 0; k0 < K; k0 += 32) {
        uint4 va0 = *(const uint4*)(A + (size_t)(m0 + srow)      * K + k0 + skq * 8);
        uint4 va1 = *(const uint4*)(A + (size_t)(m0 + srow + 64) * K + k0 + skq * 8);
        uint4 vb0 = *(const uint4*)(Bt + (size_t)(n0 + srow)      * K + k0 + skq * 8);
        uint4 vb1 = *(const uint4*)(Bt + (size_t)(n0 + srow + 64) * K + k0 + skq * 8);
        __syncthreads();
        *(uint4*)(lds_a + srow * 32 + skq * 8)        = va0;
        *(uint4*)(lds_a + (srow + 64) * 32 + skq * 8) = va1;
        *(uint4*)(lds_b + srow * 32 + skq * 8)        = vb0;
        *(uint4*)(lds_b + (srow + 64) * 32 + skq * 8) = vb1;
        __syncthreads();

        short8 af[4], bf[4];
        #pragma unroll
        for (int mt = 0; mt < 4; ++mt)
            af[mt] = *(const short8*)(lds_a + (wm + mt * 16 + r16) * 32 + q * 8);
        #pragma unroll
        for (int nt = 0; nt < 4; ++nt)
            bf[nt] = *(const short8*)(lds_b + (wn + nt * 16 + r16) * 32 + q * 8);
        #pragma unroll
        for (int mt = 0; mt < 4; ++mt)
            #pragma unroll
            for (int nt = 0; nt < 4; ++nt)
                acc[mt][nt] = __builtin_amdgcn_mfma_f32_16x16x32_bf16(
                    af[mt], bf[nt], acc[mt][nt], 0, 0, 0);
    }

    #pragma unroll
    for (int mt = 0; mt < 4; ++mt)
        #pragma unroll
        for (int nt = 0; nt < 4; ++nt) {
            int gcol = n0 + wn + nt * 16 + r16;
            #pragma unroll
            for (int r = 0; r < 4; ++r) {
                int grow = m0 + wm + mt * 16 + q * 4 + r;
                float v = acc[mt][nt][r];
                if (EPI == 1) {
                    v += bias[gcol];
                    v = (v > 20.f) ? v : log1pf(__expf(v));
                }
                if (EPI == 2) {
                    v += bias[grow];
                    v = (v > 20.f) ? v : log1pf(__expf(v));
                }
                C[(size_t)grow * N + gcol] = v;
            }
        }
}

// ---------- causal depthwise conv (K=4) + silu, tiled ----------
// Writes xssm_b bf16 [b*L+t][d] (for GEMM2) and xssm_t f32 [d][b][t] (for scan).
__global__ void conv_silu_v2(const float* __restrict__ xz, const float* __restrict__ cw,
                             const float* __restrict__ cb, u16* __restrict__ xbf,
                             float* __restrict__ xt_out) {
    __shared__ float xt[35][33];
    __shared__ float ot[32][33];
    const int b = blockIdx.z;
    const int d0 = blockIdx.x * 32;
    const int t0 = blockIdx.y * 32;
    const int tx = threadIdx.x, ty = threadIdx.y;  // 32 x 8

    for (int i = ty; i < 35; i += 8) {
        int t = t0 - 3 + i;
        float v = (t >= 0) ? xz[((size_t)(b * 2048 + t)) * 4096 + d0 + tx] : 0.f;
        xt[i][tx] = v;
    }
    __syncthreads();

    const int d = d0 + tx;
    const float w0 = cw[d * 4 + 0], w1 = cw[d * 4 + 1], w2 = cw[d * 4 + 2], w3 = cw[d * 4 + 3];
    const float cbv = cb[d];
    #pragma unroll
    for (int j = 0; j < 4; ++j) {
        int tt = ty + 8 * j;
        float s = cbv + xt[tt][tx] * w0 + xt[tt + 1][tx] * w1
                      + xt[tt + 2][tx] * w2 + xt[tt + 3][tx] * w3;
        float v = silu(s);
        xbf[((size_t)(b * 2048 + t0 + tt)) * 2048 + d] = f2bf(v);
        ot[tt][tx] = v;
    }
    __syncthreads();
    #pragma unroll
    for (int j = 0; j < 4; ++j) {
        int dd = d0 + ty + 8 * j;
        xt_out[((size_t)dd * 2 + b) * 2048 + t0 + tx] = ot[tx][ty + 8 * j];
    }
}

// ---------- extract dt_r (cols 0..63 of x_dbl) as bf16 ----------
__global__ void cvt_dtr_kernel(const float* __restrict__ xdbl, u16* __restrict__ dtr) {
    int idx = blockIdx.x * 256 + threadIdx.x;  // < 4096*64
    int row = idx >> 6, c = idx & 63;
    dtr[idx] = f2bf(xdbl[(size_t)row * 256 + c]);
}

// ---------- selective scan, chunked two-pass ----------
// Layouts: dt_t, x_t, y_t : [d][b][t]  (row = d*2+b, contiguous in t)
//          hseed : [c][b][d][n], Ssum : [c][b][d]
// 16 lanes per (d) row, 4 states/lane; 4 rows/wave; 4 waves/block = 16 d per block.
// Grid: (128 d-blocks, 8 chunks, 2 b). T = 256 steps per chunk.

__global__ __launch_bounds__(256, 8) void scan_phase1(
    const float* __restrict__ dt_t, const float* __restrict__ x_t,
    const float* __restrict__ xdbl, const float* __restrict__ A_log,
    float* __restrict__ hseed, float* __restrict__ Ssum)
{
    const int tid = threadIdx.x;
    const int lane = tid & 63, wave = tid >> 6;
    const int g = lane & 15, rw = lane >> 4;
    const int d = blockIdx.x * 16 + wave * 4 + rw;
    const int c = blockIdx.y, b = blockIdx.z;
    const int t0 = c * 256;

    float a2[4];
    #pragma unroll
    for (int k = 0; k < 4; ++k)
        a2[k] = -__expf(A_log[d * 64 + 4 * g + k]) * LOG2E;

    const float* dt_p = dt_t + ((size_t)d * 2 + b) * 2048 + t0;
    const float* x_p  = x_t  + ((size_t)d * 2 + b) * 2048 + t0;
    const float* B_p  = xdbl + ((size_t)(b * 2048 + t0)) * 256 + 64 + 4 * g;

    float h0 = 0.f, h1 = 0.f, h2 = 0.f, h3 = 0.f, S = 0.f;
    float dt_v = dt_p[0], x_v = x_p[0];
    float4 Bv = *(const float4*)B_p;

    for (int t = 0; t < 256; ++t) {
        int t2 = (t < 255) ? t + 1 : 255;
        float dt_n = dt_p[t2];
        float x_n  = x_p[t2];
        float4 B_n = *(const float4*)(B_p + (size_t)t2 * 256);

        float dtx = dt_v * x_v;
        S += dt_v;
        h0 = fmaf(exp2f(a2[0] * dt_v), h0, dtx * Bv.x);
        h1 = fmaf(exp2f(a2[1] * dt_v), h1, dtx * Bv.y);
        h2 = fmaf(exp2f(a2[2] * dt_v), h2, dtx * Bv.z);
        h3 = fmaf(exp2f(a2[3] * dt_v), h3, dtx * Bv.w);

        dt_v = dt_n; x_v = x_n; Bv = B_n;
    }

    size_t hbase = (((size_t)c * 2 + b) * 2048 + d) * 64 + 4 * g;
    *(float4*)(hseed + hbase) = (float4){h0, h1, h2, h3};
    if (g == 0) Ssum[((size_t)c * 2 + b) * 2048 + d] = S;
}

// h_in[c+1] = exp(A*S_c) * h_in[c] + h_out_local[c]; rewrite hseed[c] with h_in[c].
__global__ void scan_combine(float* __restrict__ hseed, const float* __restrict__ Ssum,
                             const float* __restrict__ A_log) {
    int idx = blockIdx.x * 256 + threadIdx.x;   // (b*2048 + d)*64 + n, < 262144
    int n = idx & 63;
    int d = (idx >> 6) & 2047;
    int b = idx >> 17;
    float a2 = -__expf(A_log[d * 64 + n]) * LOG2E;
    float h = 0.f;
    for (int c = 0; c < 8; ++c) {
        size_t base = (((size_t)c * 2 + b) * 2048 + d) * 64 + n;
        float hout = hseed[base];
        hseed[base] = h;
        float S = Ssum[((size_t)c * 2 + b) * 2048 + d];
        h = exp2f(a2 * S) * h + hout;
    }
}

__global__ __launch_bounds__(256, 8) void scan_phase2(
    const float* __restrict__ dt_t, const float* __restrict__ x_t,
    const float* __restrict__ xdbl, const float* __restrict__ A_log,
    const float* __restrict__ hseed, const float* __restrict__ Dp,
    float* __restrict__ y_t)
{
    const int tid = threadIdx.x;
    const int lane = tid & 63, wave = tid >> 6;
    const int g = lane & 15, rw = lane >> 4;
    const int d = blockIdx.x * 16 + wave * 4 + rw;
    const int c = blockIdx.y, b = blockIdx.z;
    const int t0 = c * 256;

    float a2[4];
    #pragma unroll
    for (int k = 0; k < 4; ++k)
        a2[k] = -__expf(A_log[d * 64 + 4 * g + k]) * LOG2E;

    const float* dt_p = dt_t + ((size_t)d * 2 + b) * 2048 + t0;
    const float* x_p  = x_t  + ((size_t)d * 2 + b) * 2048 + t0;
    float*       y_p  = y_t  + ((size_t)d * 2 + b) * 2048 + t0;
    const float* B_p  = xdbl + ((size_t)(b * 2048 + t0)) * 256 + 64 + 4 * g;
    const float* C_p  = B_p + 64;
    const float Dd = Dp[d];

    size_t hbase = (((size_t)c * 2 + b) * 2048 + d) * 64 + 4 * g;
    float4 hv = *(const float4*)(hseed + hbase);
    float h0 = hv.x, h1 = hv.y, h2 = hv.z, h3 = hv.w;

    float dt_v = dt_p[0], x_v = x_p[0];
    float4 Bv = *(const float4*)B_p;
    float4 Cv = *(const float4*)C_p;

    for (int t = 0; t < 256; ++t) {
        int t2 = (t < 255) ? t + 1 : 255;
        float dt_n = dt_p[t2];
        float x_n  = x_p[t2];
        float4 B_n = *(const float4*)(B_p + (size_t)t2 * 256);
        float4 C_n = *(const float4*)(C_p + (size_t)t2 * 256);

        float dtx = dt_v * x_v;
        h0 = fmaf(exp2f(a2[0] * dt_v), h0, dtx * Bv.x);
        h1 = fmaf(exp2f(a2[1] * dt_v), h1, dtx * Bv.y);
        h2 = fmaf(exp2f(a2[2] * dt_v), h2, dtx * Bv.z);
        h3 = fmaf(exp2f(a2[3] * dt_v), h3, dtx * Bv.w);
        float p = fmaf(h0, Cv.x, fmaf(h1, Cv.y, fmaf(h2, Cv.z, h3 * Cv.w)));
        p += __shfl_xor(p, 1, 64);
        p += __shfl_xor(p, 2, 64);
        p += __shfl_xor(p, 4, 64);
        p += __shfl_xor(p, 8, 64);
        if (g == 0) y_p[t] = fmaf(x_v, Dd, p);

        dt_v = dt_n; x_v = x_n; Bv = B_n; Cv = C_n;
    }
}

// ---------- fused transpose + gate: yf[b*L+t][d] = bf16( y_t[d][b][t] * silu(z[b,t,d]) ) ----------
__global__ void fuse_transpose(const float* __restrict__ y_t, const float* __restrict__ xz,
                               u16* __restrict__ yf) {
    __shared__ float tile[32][33];
    const int b = blockIdx.z;
    const int d0 = blockIdx.x * 32;
    const int t0 = blockIdx.y * 32;
    const int tx = threadIdx.x, ty = threadIdx.y;  // 32 x 8
    #pragma unroll
    for (int i = 0; i < 32; i += 8) {
        int dd = d0 + ty + i;
        tile[ty + i][tx] = y_t[((size_t)dd * 2 + b) * 2048 + t0 + tx];
    }
    __syncthreads();
    #pragma unroll
    for (int i = 0; i < 32; i += 8) {
        int t = t0 + ty + i, d = d0 + tx;
        float z = xz[((size_t)(b * 2048 + t)) * 4096 + 2048 + d];
        float y = tile[tx][ty + i];
        yf[((size_t)(b * 2048 + t)) * 2048 + d] = f2bf(y * silu(z));
    }
}

// ---------- host launch ----------
extern "C" void kernel_launch(void* const* d_in, const int* in_sizes, int n_in,
                              void* d_out, int out_size, void* d_ws, size_t ws_size,
                              hipStream_t stream) {
    const float* u     = (const float*)d_in[0];
    const float* W_in  = (const float*)d_in[1];
    const float* convw = (const float*)d_in[2];
    const float* convb = (const float*)d_in[3];
    const float* W_x   = (const float*)d_in[4];
    const float* W_dt  = (const float*)d_in[5];
    const float* b_dt  = (const float*)d_in[6];
    const float* A_log = (const float*)d_in[7];
    const float* Dvec  = (const float*)d_in[8];
    const float* W_out = (const float*)d_in[9];
    float* out = (float*)d_out;

    char* w = (char*)d_ws;
    size_t off = 0;
    auto alloc = [&](size_t bytes) -> void* {
        void* p = w + off;
        off = (off + bytes + 255) & ~(size_t)255;
        return p;
    };
    u16*   u_bf   = (u16*)  alloc((size_t)4096 * 1024 * 2);
    u16*   WinT   = (u16*)  alloc((size_t)4096 * 1024 * 2);
    u16*   WxT    = (u16*)  alloc((size_t)256 * 2048 * 2);
    u16*   WdtT   = (u16*)  alloc((size_t)2048 * 64 * 2);
    u16*   WoutT  = (u16*)  alloc((size_t)1024 * 2048 * 2);
    float* xz     = (float*)alloc((size_t)4096 * 4096 * 4);
    float* xssm_t = (float*)alloc((size_t)4096 * 2048 * 4);   // [d][b][t]
    u16*   xssm_b = (u16*)  alloc((size_t)4096 * 2048 * 2);   // [b*L+t][d]
    float* xdbl   = (float*)alloc((size_t)4096 * 256 * 4);
    u16*   dtr_bf = (u16*)  alloc((size_t)4096 * 64 * 2);
    float* dt_t   = (float*)alloc((size_t)4096 * 2048 * 4);   // [d][b][t]
    float* hseed  = (float*)alloc((size_t)8 * 2 * 2048 * 64 * 4);
    float* Ssum   = (float*)alloc((size_t)8 * 2 * 2048 * 4);
    float* y_t    = (float*)alloc((size_t)4096 * 2048 * 4);   // [d][b][t]
    u16*   yf     = (u16*)  alloc((size_t)4096 * 2048 * 2);

    // pre-passes: convert / transpose weights to bf16
    cvt_f32_bf16<<<16384, 256, 0, stream>>>(u, u_bf, 4096 * 1024);
    transpose_cvt<<<dim3(128, 32), dim3(32, 8), 0, stream>>>(W_in, WinT, 1024, 4096, 4096);
    transpose_cvt<<<dim3(8, 64),  dim3(32, 8), 0, stream>>>(W_x,   WxT,  2048, 192, 256);
    transpose_cvt<<<dim3(64, 2),  dim3(32, 8), 0, stream>>>(W_dt,  WdtT, 64, 2048, 2048);
    transpose_cvt<<<dim3(32, 64), dim3(32, 8), 0, stream>>>(W_out, WoutT, 2048, 1024, 1024);

    // GEMM1: xz = u @ W_in   [4096,1024]x[1024,4096]
    gemm_bf16<0><<<dim3(32, 32), 256, 0, stream>>>(u_bf, WinT, xz, 4096, 4096, 1024, nullptr);

    // conv + silu (tiled; emits bf16 [b,t,d] and f32 [d][b][t])
    conv_silu_v2<<<dim3(64, 64, 2), dim3(32, 8), 0, stream>>>(xz, convw, convb, xssm_b, xssm_t);

    // GEMM2: x_dbl = x_ssm @ W_x (N padded 192->256)
    gemm_bf16<0><<<dim3(2, 32), 256, 0, stream>>>(xssm_b, WxT, xdbl, 4096, 256, 2048, nullptr);

    // dt_r -> bf16
    cvt_dtr_kernel<<<1024, 256, 0, stream>>>(xdbl, dtr_bf);

    // GEMM3 (transposed output): dt_t[d][b*L+t] = softplus(W_dt^T @ dt_r^T + b_dt[d])
    //   A = WdtT [2048 x 64], Bt = dtr_bf [4096 x 64], M=2048, N=4096, K=64
    gemm_bf16<2><<<dim3(32, 16), 256, 0, stream>>>(WdtT, dtr_bf, dt_t, 2048, 4096, 64, b_dt);

    // chunked selective scan
    scan_phase1<<<dim3(128, 8, 2), 256, 0, stream>>>(dt_t, xssm_t, xdbl, A_log, hseed, Ssum);
    scan_combine<<<1024, 256, 0, stream>>>(hseed, Ssum, A_log);
    scan_phase2<<<dim3(128, 8, 2), 256, 0, stream>>>(dt_t, xssm_t, xdbl, A_log, hseed, Dvec, y_t);

    // yf = bf16( y_t * silu(z) ), transposed back to [b*L+t][d]
    fuse_transpose<<<dim3(64, 64, 2), dim3(32, 8), 0, stream>>>(y_t, xz, yf);

    // GEMM4: out = yf @ W_out
    gemm_bf16<0><<<dim3(8, 32), 256, 0, stream>>>(yf, WoutT, out, 4096, 1024, 2048, nullptr);
}